// Round 5
// baseline (115.847 us; speedup 1.0000x reference)
//
#include <hip/hip_runtime.h>

#define HH 479
#define WW 639
#define BATCH 8
#define NACC 64   // accumulator slots (reduce same-line atomic contention)

// Separable moments per (output-row i, window-col c):
//   S1=SUM d^2, Sb=SUM b d^2, Sbb=SUM b^2 d^2, T1=SUM d, Tb=SUM b d  (8 rows)
// Per pixel combine over 8 window-cols with weights {1, a, a^2}.
//
// Solve (all f32): reference solves (M+eps I) n = s then normalizes. With
// A_hat = M + eps I - s s^T/64 (PD even under zero-padding, since
// s s^T/64 <= s s^T/N_eff in PSD order), Sherman-Morrison gives
// (M+eps I)^-1 s = A_hat^-1 s * 1/(1 + s^T A_hat^-1 s / 64), a POSITIVE
// scalar multiple -> identical unit normal. A_hat is centered (entries
// O(variance)) so f32 cofactors lose ~1e3 cancellation, not ~1e8, and
// det(A_hat) > 0 always -> no det-sign branch.
//
// Retirement: fire-and-forget atomicAdd into acc[block%64] (round 2/3 showed
// fence+counter readback serializes retirement device-wide, +130 us).

__device__ __forceinline__ void solve_normal(
    float xx, float xy, float xz, float yy, float yz, float zz,
    float xs, float ys, float zs,
    float a_c, float b_c, float d0,
    float* nx, float* ny, float* nz)
{
    const float EPSV = 1e-6f;
    const float inv64 = 1.0f / 64.0f;
    float hx = xs * inv64, hy = ys * inv64, hz = zs * inv64;
    float cxx = fmaf(-hx, xs, xx) + EPSV;
    float cxy = fmaf(-hx, ys, xy);
    float cxz = fmaf(-hx, zs, xz);
    float cyy = fmaf(-hy, ys, yy) + EPSV;
    float cyz = fmaf(-hy, zs, yz);
    float czz = fmaf(-hz, zs, zz) + EPSV;
    // adjugate (symmetric)
    float c00 = fmaf(cyy, czz, -cyz * cyz);
    float c01 = fmaf(cxz, cyz, -cxy * czz);
    float c02 = fmaf(cxy, cyz, -cxz * cyy);
    float c11 = fmaf(cxx, czz, -cxz * cxz);
    float c12 = fmaf(cxy, cxz, -cxx * cyz);
    float c22 = fmaf(cxx, cyy, -cxy * cxy);
    float m0 = fmaf(c00, xs, fmaf(c01, ys, c02 * zs));
    float m1 = fmaf(c01, xs, fmaf(c11, ys, c12 * zs));
    float m2 = fmaf(c02, xs, fmaf(c12, ys, c22 * zs));
    float g  = fmaf(m0, a_c, fmaf(m1, b_c, m2));   // sign of dot(n, xyz) (d0>0)
    float inv = rsqrtf(fmaf(m0, m0, fmaf(m1, m1, m2 * m2)));
    if (g > 0.0f) inv = -inv;
    if (!(d0 > 0.0f)) inv = 0.0f;                  // where(depth>0, n, 0)
    *nx = m0 * inv; *ny = m1 * inv; *nz = m2 * inv;
}

// record address: 6 dwords/entry + 2-dword skip every 16 entries.
// bank = (6r + 2q) mod 32 for entry 16q+r -> lanes 16 entries apart no longer
// share a bank (the stride-6 4-way alignment collision from round 4).
__device__ __forceinline__ int rec_addr(int t) { return 6 * t + 2 * (t >> 4); }

__global__ __launch_bounds__(256, 4)
void ppal_main(const float* __restrict__ pred, const float* __restrict__ gt,
               double* __restrict__ acc)
{
    const int tx = threadIdx.x;        // 0..15
    const int ty = threadIdx.y;        // 0..15
    const int tid = ty * 16 + tx;
    const int j0 = blockIdx.x * 16;
    const int i0 = blockIdx.y * 16;
    const int b  = blockIdx.z;

    const float invFX = 1.0f / 518.857f;
    const float invFY = 1.0f / 519.469f;

    // depth tile rows i0-4..i0+18 (23), cols j0-4..j0+18 (23); stride 24
    __shared__ float sd[2][23 * 24];
    // column-sum records: entry t=i*24+c -> {S1,Sb,Sbb,T1,Tb,pad} at rec_addr(t)
    __shared__ float cs[2][6 * 384 + 2 * 24];

    const float* src0 = pred + (size_t)b * (HH * WW);
    const float* src1 = gt   + (size_t)b * (HH * WW);
    for (int idx = tid; idx < 23 * 24; idx += 256) {
        int lr = idx / 24, lc = idx - lr * 24;
        int r = i0 - 4 + lr, c = j0 - 4 + lc;
        bool ok = (lc < 23) && (r >= 0) && (r < HH) && (c >= 0) && (c < WW);
        int off = r * WW + c;
        sd[0][idx] = ok ? src0[off] : 0.0f;
        sd[1][idx] = ok ? src1[off] : 0.0f;
    }
    __syncthreads();

    // ---- stage 1: row reductions; tasks t: i=t/24, c=t%24 ----
    for (int t = tid; t < 384; t += 256) {
        int i = t / 24;
        int c = t - i * 24;
        float S1[2] = {0.f, 0.f}, Sb[2] = {0.f, 0.f}, Sbb[2] = {0.f, 0.f};
        float T1[2] = {0.f, 0.f}, Tb[2] = {0.f, 0.f};
#pragma unroll
        for (int dr = 0; dr < 8; ++dr) {
            float bv = ((float)(i0 + i - 4 + dr) - 239.5f) * invFY;
#pragma unroll
            for (int k = 0; k < 2; ++k) {
                float d  = sd[k][(i + dr) * 24 + c];
                float bd = bv * d;
                T1[k] += d;
                Tb[k] += bd;
                S1[k]  = fmaf(d,  d,  S1[k]);
                Sb[k]  = fmaf(bd, d,  Sb[k]);
                Sbb[k] = fmaf(bd, bd, Sbb[k]);
            }
        }
        int ra = rec_addr(t);
#pragma unroll
        for (int k = 0; k < 2; ++k) {
            float* e = &cs[k][ra];
            *(float2*)(e)     = make_float2(S1[k], Sb[k]);
            *(float2*)(e + 2) = make_float2(Sbb[k], T1[k]);
            e[4] = Tb[k];
        }
    }
    __syncthreads();

    // ---- stage 2: per-pixel column combine + solve ----
    const int i = i0 + ty, j = j0 + tx;
    const bool valid = (i < HH) && (j < WW);

    float contrib = 0.0f;
    if (valid) {
        float aa[8], a2[8];
#pragma unroll
        for (int dc = 0; dc < 8; ++dc) {
            float a = ((float)(j - 4 + dc) - 319.5f) * invFX;
            aa[dc] = a;
            a2[dc] = a * a;
        }
        float bc = ((float)i - 239.5f) * invFY;
        const int ebase = ty * 24 + tx;

        float n2[2][3];
#pragma unroll
        for (int k = 0; k < 2; ++k) {
            float xx = 0.f, xy = 0.f, xz = 0.f, yy = 0.f, yz = 0.f, zz = 0.f;
            float xs = 0.f, ys = 0.f, zs = 0.f;
#pragma unroll
            for (int dc = 0; dc < 8; ++dc) {
                const float* e = &cs[k][rec_addr(ebase + dc)];
                float2 p01 = *(const float2*)(e);       // S1, Sb
                float2 p23 = *(const float2*)(e + 2);   // Sbb, T1
                float  tb  = e[4];                      // Tb
                zz += p01.x;  yz += p01.y;  yy += p23.x;
                zs += p23.y;  ys += tb;
                xz = fmaf(aa[dc], p01.x, xz);
                xy = fmaf(aa[dc], p01.y, xy);
                xs = fmaf(aa[dc], p23.y, xs);
                xx = fmaf(a2[dc], p01.x, xx);
            }
            float d0 = sd[k][(ty + 4) * 24 + (tx + 4)];
            solve_normal(xx, xy, xz, yy, yz, zz, xs, ys, zs,
                         aa[4], bc, d0, &n2[k][0], &n2[k][1], &n2[k][2]);
        }
        contrib = fabsf(n2[0][0] - n2[1][0])
                + fabsf(n2[0][1] - n2[1][1])
                + fabsf(n2[0][2] - n2[1][2]);
    }

    // ---- reduce: wave shuffle -> LDS -> ONE fire-and-forget atomic/block ----
    float v = contrib;
#pragma unroll
    for (int off = 32; off > 0; off >>= 1) v += __shfl_down(v, off, 64);
    __shared__ float wsum[4];
    int wid = tid >> 6, lane = tid & 63;
    if (lane == 0) wsum[wid] = v;
    __syncthreads();
    if (tid == 0) {
        double bs = (double)wsum[0] + (double)wsum[1] + (double)wsum[2] + (double)wsum[3];
        int slot = (blockIdx.x + 40 * blockIdx.y + 1200 * blockIdx.z) & (NACC - 1);
        atomicAdd(&acc[slot], bs);
    }
}

__global__ void ppal_finalize(const double* __restrict__ acc, float* __restrict__ out)
{
    int lane = threadIdx.x;            // 64 threads
    double v = acc[lane];
#pragma unroll
    for (int off = 32; off > 0; off >>= 1) v += __shfl_down(v, off, 64);
    if (lane == 0)
        out[0] = (float)(v * (1.0 / 7345944.0));  // mean over B*3*H*W
}

extern "C" void kernel_launch(void* const* d_in, const int* in_sizes, int n_in,
                              void* d_out, int out_size, void* d_ws, size_t ws_size,
                              hipStream_t stream)
{
    const float* pred = (const float*)d_in[0];
    const float* gt   = (const float*)d_in[1];
    float* out  = (float*)d_out;
    double* acc = (double*)d_ws;

    hipMemsetAsync(acc, 0, NACC * sizeof(double), stream);

    dim3 grid((WW + 15) / 16, (HH + 15) / 16, BATCH);  // 40 x 30 x 8 = 9600
    dim3 block(16, 16);
    ppal_main<<<grid, block, 0, stream>>>(pred, gt, acc);
    ppal_finalize<<<1, 64, 0, stream>>>(acc, out);
}

// Round 6
// 112.561 us; speedup vs baseline: 1.0292x; 1.0292x over previous
//
#include <hip/hip_runtime.h>

#define HH 479
#define WW 639
#define BATCH 8
#define NACC 64   // accumulator slots (reduce same-line atomic contention)

// Separable moments per (output-row i, window-col c):
//   S1=SUM d^2, Sb=SUM b d^2, Sbb=SUM b^2 d^2, T1=SUM d, Tb=SUM b d  (8 rows)
// Per pixel combine over 8 window-cols with weights {1, a, a^2}.
//
// Solve (all f32): reference solves (M+eps I) n = s then normalizes. With
// A_hat = M + eps I - s s^T/64 (PD even under zero-padding), Sherman-Morrison
// gives (M+eps I)^-1 s = A_hat^-1 s * positive scalar -> identical unit
// normal. Centered A_hat kills the ~1e8 cofactor cancellation; det>0 always.
// Validated round 5: absmax 0.0.
//
// LDS: plain stride-6 records (round 4 layout). Round 5's +2*(t>>4) swizzle
// REGRESSED conflicts 3.0M->8.8M (broke within-row bank distinctness); any
// even-stride swizzle keeps records on even banks, so round-4 layout is the
// best AoS-6 can do.
//
// Retirement: fire-and-forget atomicAdd into acc[block%64] (round 2/3:
// fence+counter readback serializes block retirement device-wide, +130 us).

__device__ __forceinline__ void solve_normal(
    float xx, float xy, float xz, float yy, float yz, float zz,
    float xs, float ys, float zs,
    float a_c, float b_c, float d0,
    float* nx, float* ny, float* nz)
{
    const float EPSV = 1e-6f;
    const float inv64 = 1.0f / 64.0f;
    float hx = xs * inv64, hy = ys * inv64, hz = zs * inv64;
    float cxx = fmaf(-hx, xs, xx) + EPSV;
    float cxy = fmaf(-hx, ys, xy);
    float cxz = fmaf(-hx, zs, xz);
    float cyy = fmaf(-hy, ys, yy) + EPSV;
    float cyz = fmaf(-hy, zs, yz);
    float czz = fmaf(-hz, zs, zz) + EPSV;
    // adjugate (symmetric)
    float c00 = fmaf(cyy, czz, -cyz * cyz);
    float c01 = fmaf(cxz, cyz, -cxy * czz);
    float c02 = fmaf(cxy, cyz, -cxz * cyy);
    float c11 = fmaf(cxx, czz, -cxz * cxz);
    float c12 = fmaf(cxy, cxz, -cxx * cyz);
    float c22 = fmaf(cxx, cyy, -cxy * cxy);
    float m0 = fmaf(c00, xs, fmaf(c01, ys, c02 * zs));
    float m1 = fmaf(c01, xs, fmaf(c11, ys, c12 * zs));
    float m2 = fmaf(c02, xs, fmaf(c12, ys, c22 * zs));
    float g  = fmaf(m0, a_c, fmaf(m1, b_c, m2));   // sign of dot(n, xyz) (d0>0)
    float inv = rsqrtf(fmaf(m0, m0, fmaf(m1, m1, m2 * m2)));
    if (g > 0.0f) inv = -inv;
    if (!(d0 > 0.0f)) inv = 0.0f;                  // where(depth>0, n, 0)
    *nx = m0 * inv; *ny = m1 * inv; *nz = m2 * inv;
}

__global__ __launch_bounds__(256, 4)
void ppal_main(const float* __restrict__ pred, const float* __restrict__ gt,
               double* __restrict__ acc)
{
    const int tx = threadIdx.x;        // 0..15
    const int ty = threadIdx.y;        // 0..15
    const int tid = ty * 16 + tx;
    const int j0 = blockIdx.x * 16;
    const int i0 = blockIdx.y * 16;
    const int b  = blockIdx.z;

    const float invFX = 1.0f / 518.857f;
    const float invFY = 1.0f / 519.469f;

    // depth tile rows i0-4..i0+18 (23), cols j0-4..j0+18 (23); stride 24
    __shared__ float sd[2][23 * 24];
    // column sums, entry e=i*24+c: dw{0..4}={S1,Sb,Sbb,T1,Tb}, dw5 pad
    __shared__ float cs[2][384][6];

    const float* src0 = pred + (size_t)b * (HH * WW);
    const float* src1 = gt   + (size_t)b * (HH * WW);
    for (int idx = tid; idx < 23 * 24; idx += 256) {
        int lr = idx / 24, lc = idx - lr * 24;
        int r = i0 - 4 + lr, c = j0 - 4 + lc;
        bool ok = (lc < 23) && (r >= 0) && (r < HH) && (c >= 0) && (c < WW);
        int off = r * WW + c;
        sd[0][idx] = ok ? src0[off] : 0.0f;
        sd[1][idx] = ok ? src1[off] : 0.0f;
    }
    __syncthreads();

    // ---- stage 1: row reductions; tasks t: i=t/24, c=t%24 ----
    for (int t = tid; t < 384; t += 256) {
        int i = t / 24;
        int c = t - i * 24;
        float S1[2] = {0.f, 0.f}, Sb[2] = {0.f, 0.f}, Sbb[2] = {0.f, 0.f};
        float T1[2] = {0.f, 0.f}, Tb[2] = {0.f, 0.f};
#pragma unroll
        for (int dr = 0; dr < 8; ++dr) {
            float bv = ((float)(i0 + i - 4 + dr) - 239.5f) * invFY;
#pragma unroll
            for (int k = 0; k < 2; ++k) {
                float d  = sd[k][(i + dr) * 24 + c];
                float bd = bv * d;
                T1[k] += d;
                Tb[k] += bd;
                S1[k]  = fmaf(d,  d,  S1[k]);
                Sb[k]  = fmaf(bd, d,  Sb[k]);
                Sbb[k] = fmaf(bd, bd, Sbb[k]);
            }
        }
#pragma unroll
        for (int k = 0; k < 2; ++k) {
            float* e = cs[k][t];
            *(float2*)(e)     = make_float2(S1[k], Sb[k]);
            *(float2*)(e + 2) = make_float2(Sbb[k], T1[k]);
            e[4] = Tb[k];
        }
    }
    __syncthreads();

    // ---- stage 2: per-pixel column combine + solve ----
    const int i = i0 + ty, j = j0 + tx;
    const bool valid = (i < HH) && (j < WW);

    float contrib = 0.0f;
    if (valid) {
        float aa[8], a2[8];
#pragma unroll
        for (int dc = 0; dc < 8; ++dc) {
            float a = ((float)(j - 4 + dc) - 319.5f) * invFX;
            aa[dc] = a;
            a2[dc] = a * a;
        }
        float bc = ((float)i - 239.5f) * invFY;
        const int ebase = ty * 24 + tx;

        float n2[2][3];
#pragma unroll
        for (int k = 0; k < 2; ++k) {
            float xx = 0.f, xy = 0.f, xz = 0.f, yy = 0.f, yz = 0.f, zz = 0.f;
            float xs = 0.f, ys = 0.f, zs = 0.f;
#pragma unroll
            for (int dc = 0; dc < 8; ++dc) {
                const float* e = cs[k][ebase + dc];
                float2 p01 = *(const float2*)(e);       // S1, Sb
                float2 p23 = *(const float2*)(e + 2);   // Sbb, T1
                float  tb  = e[4];                      // Tb
                zz += p01.x;  yz += p01.y;  yy += p23.x;
                zs += p23.y;  ys += tb;
                xz = fmaf(aa[dc], p01.x, xz);
                xy = fmaf(aa[dc], p01.y, xy);
                xs = fmaf(aa[dc], p23.y, xs);
                xx = fmaf(a2[dc], p01.x, xx);
            }
            float d0 = sd[k][(ty + 4) * 24 + (tx + 4)];
            solve_normal(xx, xy, xz, yy, yz, zz, xs, ys, zs,
                         aa[4], bc, d0, &n2[k][0], &n2[k][1], &n2[k][2]);
        }
        contrib = fabsf(n2[0][0] - n2[1][0])
                + fabsf(n2[0][1] - n2[1][1])
                + fabsf(n2[0][2] - n2[1][2]);
    }

    // ---- reduce: wave shuffle -> LDS -> ONE fire-and-forget atomic/block ----
    float v = contrib;
#pragma unroll
    for (int off = 32; off > 0; off >>= 1) v += __shfl_down(v, off, 64);
    __shared__ float wsum[4];
    int wid = tid >> 6, lane = tid & 63;
    if (lane == 0) wsum[wid] = v;
    __syncthreads();
    if (tid == 0) {
        double bs = (double)wsum[0] + (double)wsum[1] + (double)wsum[2] + (double)wsum[3];
        int slot = (blockIdx.x + 40 * blockIdx.y + 1200 * blockIdx.z) & (NACC - 1);
        atomicAdd(&acc[slot], bs);
    }
}

__global__ void ppal_finalize(const double* __restrict__ acc, float* __restrict__ out)
{
    int lane = threadIdx.x;            // 64 threads
    double v = acc[lane];
#pragma unroll
    for (int off = 32; off > 0; off >>= 1) v += __shfl_down(v, off, 64);
    if (lane == 0)
        out[0] = (float)(v * (1.0 / 7345944.0));  // mean over B*3*H*W
}

extern "C" void kernel_launch(void* const* d_in, const int* in_sizes, int n_in,
                              void* d_out, int out_size, void* d_ws, size_t ws_size,
                              hipStream_t stream)
{
    const float* pred = (const float*)d_in[0];
    const float* gt   = (const float*)d_in[1];
    float* out  = (float*)d_out;
    double* acc = (double*)d_ws;

    hipMemsetAsync(acc, 0, NACC * sizeof(double), stream);

    dim3 grid((WW + 15) / 16, (HH + 15) / 16, BATCH);  // 40 x 30 x 8 = 9600
    dim3 block(16, 16);
    ppal_main<<<grid, block, 0, stream>>>(pred, gt, acc);
    ppal_finalize<<<1, 64, 0, stream>>>(acc, out);
}

// Round 7
// 103.976 us; speedup vs baseline: 1.1142x; 1.0826x over previous
//
#include <hip/hip_runtime.h>

#define HH 479
#define WW 639
#define BATCH 8
#define NACC 64   // accumulator slots (reduce same-line atomic contention)

// Separable moments per (output-row i, window-col c):
//   S1=SUM d^2, Sb=SUM b d^2, Sbb=SUM b^2 d^2, T1=SUM d, Tb=SUM b d  (8 rows)
// Per pixel combine over 8 window-cols with weights {1, a, a^2}.
//
// Solve in f64 (adjugate * rhs), finish f32. NOTE (R6 lesson): the f32
// Sherman-Morrison solve is numerically fine but SLOWER end-to-end — the long
// f64 chain is what lets the scheduler hide stage-2 LDS latency. Keep f64.
//
// LDS: plain stride-6 AoS records (R4 layout — best measured; R5's swizzle
// regressed 3x on conflicts).
//
// Retirement: fire-and-forget atomicAdd into acc[block%64]; separate tiny
// finalize kernel. (R2/R3: fence+counter readback serializes retirement
// device-wide, +130 us.)
//
// R7 change vs R4: stage 2 interleaves both inputs — one merged load loop,
// two independent f64 solve chains for ILP.

__device__ __forceinline__ void solve_normal(
    float xx, float xy, float xz, float yy, float yz, float zz,
    float xs, float ys, float zs,
    float a_c, float b_c, float d0,
    float* nx, float* ny, float* nz)
{
    const double EPSV = 1e-6;
    double p = (double)xx + EPSV, q = (double)xy, r = (double)xz;
    double s = (double)yy + EPSV, t = (double)yz, u = (double)zz + EPSV;
    double c00 = s * u - t * t;
    double c01 = r * t - q * u;
    double c02 = q * t - r * s;
    double c11 = p * u - r * r;
    double c12 = q * r - p * t;
    double c22 = p * s - q * q;
    double m0 = c00 * (double)xs + c01 * (double)ys + c02 * (double)zs;
    double m1 = c01 * (double)xs + c11 * (double)ys + c12 * (double)zs;
    double m2 = c02 * (double)xs + c12 * (double)ys + c22 * (double)zs;
    float f0 = (float)m0, f1 = (float)m1, f2 = (float)m2;
    float g = fmaf(f0, a_c, fmaf(f1, b_c, f2));
    float inv = rsqrtf(fmaf(f0, f0, fmaf(f1, f1, f2 * f2)));
    if (g > 0.0f) inv = -inv;
    if (!(d0 > 0.0f)) inv = 0.0f;                    // where(depth>0, n, 0)
    *nx = f0 * inv; *ny = f1 * inv; *nz = f2 * inv;
}

__global__ __launch_bounds__(256, 4)
void ppal_main(const float* __restrict__ pred, const float* __restrict__ gt,
               double* __restrict__ acc)
{
    const int tx = threadIdx.x;        // 0..15
    const int ty = threadIdx.y;        // 0..15
    const int tid = ty * 16 + tx;
    const int j0 = blockIdx.x * 16;
    const int i0 = blockIdx.y * 16;
    const int b  = blockIdx.z;

    const float invFX = 1.0f / 518.857f;
    const float invFY = 1.0f / 519.469f;

    // depth tile rows i0-4..i0+18 (23), cols j0-4..j0+18 (23); stride 24
    __shared__ float sd[2][23 * 24];
    // column sums, entry e=i*24+c: dw{0..4}={S1,Sb,Sbb,T1,Tb}, dw5 pad
    __shared__ float cs[2][384][6];

    const float* src0 = pred + (size_t)b * (HH * WW);
    const float* src1 = gt   + (size_t)b * (HH * WW);
    for (int idx = tid; idx < 23 * 24; idx += 256) {
        int lr = idx / 24, lc = idx - lr * 24;
        int r = i0 - 4 + lr, c = j0 - 4 + lc;
        bool ok = (lc < 23) && (r >= 0) && (r < HH) && (c >= 0) && (c < WW);
        int off = r * WW + c;
        sd[0][idx] = ok ? src0[off] : 0.0f;
        sd[1][idx] = ok ? src1[off] : 0.0f;
    }
    __syncthreads();

    // ---- stage 1: row reductions; tasks t: i=t/24, c=t%24 ----
    for (int t = tid; t < 384; t += 256) {
        int i = t / 24;
        int c = t - i * 24;
        float S1[2] = {0.f, 0.f}, Sb[2] = {0.f, 0.f}, Sbb[2] = {0.f, 0.f};
        float T1[2] = {0.f, 0.f}, Tb[2] = {0.f, 0.f};
#pragma unroll
        for (int dr = 0; dr < 8; ++dr) {
            float bv = ((float)(i0 + i - 4 + dr) - 239.5f) * invFY;
#pragma unroll
            for (int k = 0; k < 2; ++k) {
                float d  = sd[k][(i + dr) * 24 + c];
                float bd = bv * d;
                T1[k] += d;
                Tb[k] += bd;
                S1[k]  = fmaf(d,  d,  S1[k]);
                Sb[k]  = fmaf(bd, d,  Sb[k]);
                Sbb[k] = fmaf(bd, bd, Sbb[k]);
            }
        }
#pragma unroll
        for (int k = 0; k < 2; ++k) {
            float* e = cs[k][t];
            *(float2*)(e)     = make_float2(S1[k], Sb[k]);
            *(float2*)(e + 2) = make_float2(Sbb[k], T1[k]);
            e[4] = Tb[k];
        }
    }
    __syncthreads();

    // ---- stage 2: per-pixel column combine (both inputs) + two ILP solves ----
    const int i = i0 + ty, j = j0 + tx;
    const bool valid = (i < HH) && (j < WW);

    float contrib = 0.0f;
    if (valid) {
        float aa[8], a2[8];
#pragma unroll
        for (int dc = 0; dc < 8; ++dc) {
            float a = ((float)(j - 4 + dc) - 319.5f) * invFX;
            aa[dc] = a;
            a2[dc] = a * a;
        }
        float bc = ((float)i - 239.5f) * invFY;
        const int ebase = ty * 24 + tx;

        // hoist both center depths ahead of the combine
        float d0A = sd[0][(ty + 4) * 24 + (tx + 4)];
        float d0B = sd[1][(ty + 4) * 24 + (tx + 4)];

        float xxA = 0.f, xyA = 0.f, xzA = 0.f, yyA = 0.f, yzA = 0.f, zzA = 0.f;
        float xsA = 0.f, ysA = 0.f, zsA = 0.f;
        float xxB = 0.f, xyB = 0.f, xzB = 0.f, yyB = 0.f, yzB = 0.f, zzB = 0.f;
        float xsB = 0.f, ysB = 0.f, zsB = 0.f;
#pragma unroll
        for (int dc = 0; dc < 8; ++dc) {
            const float* eA = cs[0][ebase + dc];
            const float* eB = cs[1][ebase + dc];
            float2 pA01 = *(const float2*)(eA);
            float2 pA23 = *(const float2*)(eA + 2);
            float  tbA  = eA[4];
            float2 pB01 = *(const float2*)(eB);
            float2 pB23 = *(const float2*)(eB + 2);
            float  tbB  = eB[4];
            zzA += pA01.x;  yzA += pA01.y;  yyA += pA23.x;
            zsA += pA23.y;  ysA += tbA;
            xzA = fmaf(aa[dc], pA01.x, xzA);
            xyA = fmaf(aa[dc], pA01.y, xyA);
            xsA = fmaf(aa[dc], pA23.y, xsA);
            xxA = fmaf(a2[dc], pA01.x, xxA);
            zzB += pB01.x;  yzB += pB01.y;  yyB += pB23.x;
            zsB += pB23.y;  ysB += tbB;
            xzB = fmaf(aa[dc], pB01.x, xzB);
            xyB = fmaf(aa[dc], pB01.y, xyB);
            xsB = fmaf(aa[dc], pB23.y, xsB);
            xxB = fmaf(a2[dc], pB01.x, xxB);
        }

        float nA[3], nB[3];
        solve_normal(xxA, xyA, xzA, yyA, yzA, zzA, xsA, ysA, zsA,
                     aa[4], bc, d0A, &nA[0], &nA[1], &nA[2]);
        solve_normal(xxB, xyB, xzB, yyB, yzB, zzB, xsB, ysB, zsB,
                     aa[4], bc, d0B, &nB[0], &nB[1], &nB[2]);
        contrib = fabsf(nA[0] - nB[0])
                + fabsf(nA[1] - nB[1])
                + fabsf(nA[2] - nB[2]);
    }

    // ---- reduce: wave shuffle -> LDS -> ONE fire-and-forget atomic/block ----
    float v = contrib;
#pragma unroll
    for (int off = 32; off > 0; off >>= 1) v += __shfl_down(v, off, 64);
    __shared__ float wsum[4];
    int wid = tid >> 6, lane = tid & 63;
    if (lane == 0) wsum[wid] = v;
    __syncthreads();
    if (tid == 0) {
        double bs = (double)wsum[0] + (double)wsum[1] + (double)wsum[2] + (double)wsum[3];
        int slot = (blockIdx.x + 40 * blockIdx.y + 1200 * blockIdx.z) & (NACC - 1);
        atomicAdd(&acc[slot], bs);
    }
}

__global__ void ppal_finalize(const double* __restrict__ acc, float* __restrict__ out)
{
    int lane = threadIdx.x;            // 64 threads
    double v = acc[lane];
#pragma unroll
    for (int off = 32; off > 0; off >>= 1) v += __shfl_down(v, off, 64);
    if (lane == 0)
        out[0] = (float)(v * (1.0 / 7345944.0));  // mean over B*3*H*W
}

extern "C" void kernel_launch(void* const* d_in, const int* in_sizes, int n_in,
                              void* d_out, int out_size, void* d_ws, size_t ws_size,
                              hipStream_t stream)
{
    const float* pred = (const float*)d_in[0];
    const float* gt   = (const float*)d_in[1];
    float* out  = (float*)d_out;
    double* acc = (double*)d_ws;

    hipMemsetAsync(acc, 0, NACC * sizeof(double), stream);

    dim3 grid((WW + 15) / 16, (HH + 15) / 16, BATCH);  // 40 x 30 x 8 = 9600
    dim3 block(16, 16);
    ppal_main<<<grid, block, 0, stream>>>(pred, gt, acc);
    ppal_finalize<<<1, 64, 0, stream>>>(acc, out);
}

// Round 8
// 100.657 us; speedup vs baseline: 1.1509x; 1.0330x over previous
//
#include <hip/hip_runtime.h>

#define HH 479
#define WW 639
#define BATCH 8
#define NACC 64   // accumulator slots (reduce same-line atomic contention)

// Tile: 32 cols x 16 rows per block, 256 threads, 2 px/thread (cols 2tx, 2tx+1).
// Separable moments per (output-row i, window-col c):
//   S1=SUM d^2, Sb=SUM b d^2, Sbb=SUM b^2 d^2, T1=SUM d, Tb=SUM b d  (8 rows)
// Adjacent pixels share 7/8 window columns with ABSOLUTE weights {1,a_c,a_c^2}
// -> 9 shared core sums over 7 records + 1 unique tap per pixel.
//
// Solve (f32, R5-validated): A_hat = M + eps I - s s^T/64 is PD; Sherman-
// Morrison => (M+eps I)^-1 s = A_hat^-1 s * positive scalar -> identical unit
// normal; centered A_hat kills the ~1e8 raw-moment cofactor cancellation.
// R6 showed f32 solve hurt in the 1-px structure (lost f64 latency slack);
// here 4 independent solves/thread provide that ILP instead.
//
// Retirement: fire-and-forget atomicAdd into acc[block%64] + tiny finalize
// kernel (R2/R3: fence+counter readback serializes retirement, +130 us).

__device__ __forceinline__ void solve_normal(
    float xx, float xy, float xz, float yy, float yz, float zz,
    float xs, float ys, float zs,
    float a_c, float b_c, float d0,
    float* nx, float* ny, float* nz)
{
    const float EPSV = 1e-6f;
    const float inv64 = 1.0f / 64.0f;
    float hx = xs * inv64, hy = ys * inv64, hz = zs * inv64;
    float cxx = fmaf(-hx, xs, xx) + EPSV;
    float cxy = fmaf(-hx, ys, xy);
    float cxz = fmaf(-hx, zs, xz);
    float cyy = fmaf(-hy, ys, yy) + EPSV;
    float cyz = fmaf(-hy, zs, yz);
    float czz = fmaf(-hz, zs, zz) + EPSV;
    float c00 = fmaf(cyy, czz, -cyz * cyz);
    float c01 = fmaf(cxz, cyz, -cxy * czz);
    float c02 = fmaf(cxy, cyz, -cxz * cyy);
    float c11 = fmaf(cxx, czz, -cxz * cxz);
    float c12 = fmaf(cxy, cxz, -cxx * cyz);
    float c22 = fmaf(cxx, cyy, -cxy * cxy);
    float m0 = fmaf(c00, xs, fmaf(c01, ys, c02 * zs));
    float m1 = fmaf(c01, xs, fmaf(c11, ys, c12 * zs));
    float m2 = fmaf(c02, xs, fmaf(c12, ys, c22 * zs));
    float g  = fmaf(m0, a_c, fmaf(m1, b_c, m2));   // sign of dot(n, xyz), d0>0
    float inv = rsqrtf(fmaf(m0, m0, fmaf(m1, m1, m2 * m2)));
    if (g > 0.0f) inv = -inv;
    if (!(d0 > 0.0f)) inv = 0.0f;                  // where(depth>0, n, 0)
    *nx = m0 * inv; *ny = m1 * inv; *nz = m2 * inv;
}

__global__ __launch_bounds__(256, 4)
void ppal_main(const float* __restrict__ pred, const float* __restrict__ gt,
               double* __restrict__ acc)
{
    const int tx = threadIdx.x;        // 0..15
    const int ty = threadIdx.y;        // 0..15
    const int tid = ty * 16 + tx;
    const int j0 = blockIdx.x * 32;
    const int i0 = blockIdx.y * 16;
    const int b  = blockIdx.z;

    const float invFX = 1.0f / 518.857f;
    const float invFY = 1.0f / 519.469f;

    // depth tile: rows i0-4..i0+18 (23), cols j0-4..j0+34 (39); stride 40
    __shared__ float sd[2][23 * 40];
    // column-sum records: entry t = i*39 + rc (i: output row 0..15,
    // rc: window col - (j0-4), 0..38); {S1,Sb,Sbb,T1,Tb,pad} stride 6
    __shared__ float cs[2][624 * 6];

    const float* src0 = pred + (size_t)b * (HH * WW);
    const float* src1 = gt   + (size_t)b * (HH * WW);
    for (int idx = tid; idx < 23 * 40; idx += 256) {
        int lr = idx / 40, lc = idx - lr * 40;
        int r = i0 - 4 + lr, c = j0 - 4 + lc;
        bool ok = (lc < 39) && (r >= 0) && (r < HH) && (c >= 0) && (c < WW);
        int off = r * WW + c;
        sd[0][idx] = ok ? src0[off] : 0.0f;
        sd[1][idx] = ok ? src1[off] : 0.0f;
    }
    __syncthreads();

    // ---- stage 1: 624 row-reduction tasks; i = t/39, rc = t%39 ----
    for (int t = tid; t < 624; t += 256) {
        int i = t / 39;
        int c = t - i * 39;
        float S1[2] = {0.f, 0.f}, Sb[2] = {0.f, 0.f}, Sbb[2] = {0.f, 0.f};
        float T1[2] = {0.f, 0.f}, Tb[2] = {0.f, 0.f};
#pragma unroll
        for (int dr = 0; dr < 8; ++dr) {
            float bv = ((float)(i0 + i - 4 + dr) - 239.5f) * invFY;
#pragma unroll
            for (int k = 0; k < 2; ++k) {
                float d  = sd[k][(i + dr) * 40 + c];
                float bd = bv * d;
                T1[k] += d;
                Tb[k] += bd;
                S1[k]  = fmaf(d,  d,  S1[k]);
                Sb[k]  = fmaf(bd, d,  Sb[k]);
                Sbb[k] = fmaf(bd, bd, Sbb[k]);
            }
        }
#pragma unroll
        for (int k = 0; k < 2; ++k) {
            float* e = &cs[k][6 * t];
            *(float2*)(e)     = make_float2(S1[k], Sb[k]);
            *(float2*)(e + 2) = make_float2(Sbb[k], T1[k]);
            e[4] = Tb[k];
        }
    }
    __syncthreads();

    // ---- stage 2: 2 px/thread, shared-core combine + 4 f32 solves ----
    const int i  = i0 + ty;
    const int jl = j0 + 2 * tx;        // pixel p: j = jl + p
    const bool valid0 = (i < HH);                     // jl <= 638 always
    const bool valid1 = (i < HH) && (jl + 1 < WW);

    // window cols m = 0..8 -> global col jl + m - 4
    float aw[9], aw2[9];
#pragma unroll
    for (int m = 0; m < 9; ++m) {
        float a = ((float)(jl + m - 4) - 319.5f) * invFX;
        aw[m] = a;
        aw2[m] = a * a;
    }
    float bc = ((float)i - 239.5f) * invFY;
    const int ebase = ty * 39 + 2 * tx;   // record entry for m=0

    float n0A[3], n1A[3];   // input-0 normals for pixels 0,1
    float contrib = 0.0f;
#pragma unroll
    for (int k = 0; k < 2; ++k) {
        // shared core: m = 1..7 (used by both pixels)
        float Sxx = 0.f, Sxy = 0.f, Sxz = 0.f, Syy = 0.f, Syz = 0.f, Szz = 0.f;
        float Sxs = 0.f, Sys = 0.f, Szs = 0.f;
#pragma unroll
        for (int m = 1; m < 8; ++m) {
            const float* e = &cs[k][6 * (ebase + m)];
            float2 p01 = *(const float2*)(e);       // S1, Sb
            float2 p23 = *(const float2*)(e + 2);   // Sbb, T1
            float  tb  = e[4];                      // Tb
            Szz += p01.x;  Syz += p01.y;  Syy += p23.x;
            Szs += p23.y;  Sys += tb;
            Sxz = fmaf(aw[m],  p01.x, Sxz);
            Sxy = fmaf(aw[m],  p01.y, Sxy);
            Sxs = fmaf(aw[m],  p23.y, Sxs);
            Sxx = fmaf(aw2[m], p01.x, Sxx);
        }

        float nn[2][3];
#pragma unroll
        for (int p = 0; p < 2; ++p) {
            int m = (p == 0) ? 0 : 8;               // unique tap
            const float* e = &cs[k][6 * (ebase + m)];
            float2 p01 = *(const float2*)(e);
            float2 p23 = *(const float2*)(e + 2);
            float  tb  = e[4];
            float xx = fmaf(aw2[m], p01.x, Sxx);
            float xy = fmaf(aw[m],  p01.y, Sxy);
            float xz = fmaf(aw[m],  p01.x, Sxz);
            float yy = Syy + p23.x;
            float yz = Syz + p01.y;
            float zz = Szz + p01.x;
            float xs = fmaf(aw[m],  p23.y, Sxs);
            float ys = Sys + tb;
            float zs = Szs + p23.y;
            float d0 = sd[k][(ty + 4) * 40 + (2 * tx + p + 4)];
            solve_normal(xx, xy, xz, yy, yz, zz, xs, ys, zs,
                         aw[4 + p], bc, d0, &nn[p][0], &nn[p][1], &nn[p][2]);
        }
        if (k == 0) {
            n0A[0] = nn[0][0]; n0A[1] = nn[0][1]; n0A[2] = nn[0][2];
            n1A[0] = nn[1][0]; n1A[1] = nn[1][1]; n1A[2] = nn[1][2];
        } else {
            float c0 = fabsf(n0A[0] - nn[0][0]) + fabsf(n0A[1] - nn[0][1])
                     + fabsf(n0A[2] - nn[0][2]);
            float c1 = fabsf(n1A[0] - nn[1][0]) + fabsf(n1A[1] - nn[1][1])
                     + fabsf(n1A[2] - nn[1][2]);
            contrib = (valid0 ? c0 : 0.0f) + (valid1 ? c1 : 0.0f);
        }
    }

    // ---- reduce: wave shuffle -> LDS -> ONE fire-and-forget atomic/block ----
    float v = contrib;
#pragma unroll
    for (int off = 32; off > 0; off >>= 1) v += __shfl_down(v, off, 64);
    __shared__ float wsum[4];
    int wid = tid >> 6, lane = tid & 63;
    if (lane == 0) wsum[wid] = v;
    __syncthreads();
    if (tid == 0) {
        double bs = (double)wsum[0] + (double)wsum[1] + (double)wsum[2] + (double)wsum[3];
        int slot = (blockIdx.x + 20 * blockIdx.y + 600 * blockIdx.z) & (NACC - 1);
        atomicAdd(&acc[slot], bs);
    }
}

__global__ void ppal_finalize(const double* __restrict__ acc, float* __restrict__ out)
{
    int lane = threadIdx.x;            // 64 threads
    double v = acc[lane];
#pragma unroll
    for (int off = 32; off > 0; off >>= 1) v += __shfl_down(v, off, 64);
    if (lane == 0)
        out[0] = (float)(v * (1.0 / 7345944.0));  // mean over B*3*H*W
}

extern "C" void kernel_launch(void* const* d_in, const int* in_sizes, int n_in,
                              void* d_out, int out_size, void* d_ws, size_t ws_size,
                              hipStream_t stream)
{
    const float* pred = (const float*)d_in[0];
    const float* gt   = (const float*)d_in[1];
    float* out  = (float*)d_out;
    double* acc = (double*)d_ws;

    hipMemsetAsync(acc, 0, NACC * sizeof(double), stream);

    dim3 grid(20, 30, BATCH);          // 32-col x 16-row tiles = 4800 blocks
    dim3 block(16, 16);
    ppal_main<<<grid, block, 0, stream>>>(pred, gt, acc);
    ppal_finalize<<<1, 64, 0, stream>>>(acc, out);
}